// Round 1
// baseline (566.583 us; speedup 1.0000x reference)
//
#include <hip/hip_runtime.h>
#include <hip/hip_bf16.h>

typedef __hip_bfloat16 bf16;
typedef short v8s __attribute__((ext_vector_type(8)));
typedef float v4f __attribute__((ext_vector_type(4)));

// ---------------- f32 -> bf16 cast ----------------
__global__ void castf2b(const float* __restrict__ in, bf16* __restrict__ out, int n) {
    int i = blockIdx.x * 256 + threadIdx.x;
    if (i < n) out[i] = __float2bfloat16(in[i]);
}

// ---------------- layernorm (D=512) -> bf16, optional row mask ----------------
__global__ __launch_bounds__(256) void ln_kernel(
    const float* __restrict__ x, const float* __restrict__ g,
    const float* __restrict__ bt, const float* __restrict__ mask,
    bf16* __restrict__ out)
{
    int row = blockIdx.x, tid = threadIdx.x;
    const float* xr = x + (size_t)row * 512;
    float v0 = xr[tid], v1 = xr[tid + 256];
    float s = v0 + v1, ss = v0 * v0 + v1 * v1;
    #pragma unroll
    for (int o = 32; o; o >>= 1) { s += __shfl_xor(s, o); ss += __shfl_xor(ss, o); }
    __shared__ float l1[4], l2[4];
    if ((tid & 63) == 0) { l1[tid >> 6] = s; l2[tid >> 6] = ss; }
    __syncthreads();
    s = l1[0] + l1[1] + l1[2] + l1[3];
    ss = l2[0] + l2[1] + l2[2] + l2[3];
    float mean = s * (1.f / 512.f);
    float var = ss * (1.f / 512.f) - mean * mean;
    float rs = rsqrtf(var + 1e-5f);
    float mk = mask ? mask[row] : 1.f;
    out[(size_t)row * 512 + tid] =
        __float2bfloat16(((v0 - mean) * rs * g[tid] + bt[tid]) * mk);
    out[(size_t)row * 512 + tid + 256] =
        __float2bfloat16(((v1 - mean) * rs * g[tid + 256] + bt[tid + 256]) * mk);
}

// ---------------- generic bf16 MFMA GEMM: C = A @ W^T (+bias +resid) ----------------
// A: [M x K] row-major bf16 (ldA), W: [N x K] row-major bf16 (ldW)
// C: [M x N] (ldC) fp32 or bf16. Batched via blockIdx.z: off = (z/zdiv)*s1 + (z%zdiv)*s2.
__global__ __launch_bounds__(256) void gemm_bt(
    const bf16* __restrict__ Aall, const bf16* __restrict__ Wall,
    const float* __restrict__ bias, const float* __restrict__ resid,
    void* __restrict__ Cout,
    int M, int N, int K, int ldA, int ldW, int ldC,
    long sA1, long sA2, long sW1, long sW2, long sC1, long sC2,
    int zdiv, int outbf16)
{
    __shared__ bf16 lA[128 * 40];
    __shared__ bf16 lB[128 * 40];
    int z = blockIdx.z;
    int zb = z / zdiv, zh = z - zb * zdiv;
    const bf16* A = Aall + zb * sA1 + zh * sA2;
    const bf16* W = Wall + zb * sW1 + zh * sW2;
    long coff = zb * sC1 + zh * sC2;

    int bm = blockIdx.x * 128, bn = blockIdx.y * 128;
    int tid = threadIdx.x, lane = tid & 63, wv = tid >> 6;
    int wr = (wv >> 1) * 64, wc = (wv & 1) * 64;
    int lr15 = lane & 15, lk8 = (lane >> 4) * 8;

    v4f acc[4][4] = {};
    int sr = tid >> 2, sc = (tid & 3) * 8;

    for (int k0 = 0; k0 < K; k0 += 32) {
        #pragma unroll
        for (int half = 0; half < 2; ++half) {
            int row = sr + half * 64;
            v8s av = *(const v8s*)(A + (size_t)(bm + row) * ldA + (k0 + sc));
            *(v8s*)&lA[row * 40 + sc] = av;
            v8s wvv = {0, 0, 0, 0, 0, 0, 0, 0};
            if (bn + row < N)
                wvv = *(const v8s*)(W + (size_t)(bn + row) * ldW + (k0 + sc));
            *(v8s*)&lB[row * 40 + sc] = wvv;
        }
        __syncthreads();
        v8s af[4], bfr[4];
        #pragma unroll
        for (int i = 0; i < 4; ++i)
            af[i] = *(const v8s*)&lA[(wr + i * 16 + lr15) * 40 + lk8];
        #pragma unroll
        for (int i = 0; i < 4; ++i)
            bfr[i] = *(const v8s*)&lB[(wc + i * 16 + lr15) * 40 + lk8];
        #pragma unroll
        for (int mi = 0; mi < 4; ++mi)
            #pragma unroll
            for (int ni = 0; ni < 4; ++ni)
                acc[mi][ni] = __builtin_amdgcn_mfma_f32_16x16x32_bf16(
                    af[mi], bfr[ni], acc[mi][ni], 0, 0, 0);
        __syncthreads();
    }
    // epilogue: C row = bm+wr+mi*16+(lane>>4)*4+r, col = bn+wc+ni*16+(lane&15)
    int r0 = bm + wr + (lane >> 4) * 4;
    int c0 = bn + wc + lr15;
    #pragma unroll
    for (int mi = 0; mi < 4; ++mi) {
        #pragma unroll
        for (int ni = 0; ni < 4; ++ni) {
            int col = c0 + ni * 16;
            if (col < N) {
                float bv = bias ? bias[col] : 0.f;
                #pragma unroll
                for (int r = 0; r < 4; ++r) {
                    int row = r0 + mi * 16 + r;
                    long idx = coff + (long)row * ldC + col;
                    float v = acc[mi][ni][r] + bv;
                    if (resid) v += resid[idx];
                    if (outbf16) ((bf16*)Cout)[idx] = __float2bfloat16(v);
                    else ((float*)Cout)[idx] = v;
                }
            }
        }
    }
}

// ---------------- causal depthwise conv (K=4) + bias + silu ----------------
__global__ __launch_bounds__(256) void conv_silu(
    const float* __restrict__ zx, const float* __restrict__ cw,
    const float* __restrict__ cb, float* __restrict__ out)
{
    int idx = blockIdx.x * 256 + threadIdx.x;  // B*S*1152
    if (idx >= 2 * 2048 * 1152) return;
    int c = idx % 1152;
    int t = (idx / 1152) % 2048;
    int b = idx / (1152 * 2048);
    const float* base = zx + (size_t)b * 2048 * 2184 + 1024 + c;
    float acc = cb[c];
    #pragma unroll
    for (int j = 0; j < 4; ++j) {
        int ts = t - 3 + j;
        if (ts >= 0) acc += cw[c * 4 + j] * base[(size_t)ts * 2184];
    }
    out[idx] = acc / (1.f + expf(-acc));
}

// ---------------- dt softplus + decay precompute ----------------
__global__ void dt_prep(const float* __restrict__ zx, const float* __restrict__ dt_bias,
                        const float* __restrict__ A_log,
                        float* __restrict__ dtb, float* __restrict__ decb)
{
    int i = blockIdx.x * 256 + threadIdx.x;  // 4096*8
    if (i >= 32768) return;
    int h = i & 7, row = i >> 3;
    float d = zx[(size_t)row * 2184 + 2176 + h] + dt_bias[h];
    float sp = d > 20.f ? d : log1pf(expf(d));
    dtb[i] = sp;
    decb[i] = expf(-expf(A_log[h]) * sp);
}

// ---------------- chunked SSM scan ----------------
// chunk layout: 32 chunks x 64 steps; state per (b,h,p): 64 floats in regs.
__global__ __launch_bounds__(128) void scan_p1(
    const float* __restrict__ conv, const float* __restrict__ dtb,
    const float* __restrict__ decb, const float* __restrict__ A_log,
    float* __restrict__ slocal, float* __restrict__ cdec)
{
    int chunk = blockIdx.x, bh = blockIdx.y;
    int b = bh >> 3, h = bh & 7, p = threadIdx.x;
    v4f hs[16] = {};
    const float* cb_ = conv + (size_t)b * 2048 * 1152;
    float sdt = 0.f;
    int t0 = chunk * 64;
    for (int t = 0; t < 64; ++t) {
        int tt = t0 + t;
        int ri = (b * 2048 + tt) * 8 + h;
        float dtv = dtb[ri], dec = decb[ri];
        float xv = cb_[(size_t)tt * 1152 + h * 128 + p];
        float c1 = dtv * xv;
        const v4f* Bp = (const v4f*)(cb_ + (size_t)tt * 1152 + 1024);
        #pragma unroll
        for (int i = 0; i < 16; ++i) hs[i] = hs[i] * dec + Bp[i] * c1;
        sdt += dtv;
    }
    if (p == 0) cdec[bh * 32 + chunk] = expf(-expf(A_log[h]) * sdt);
    v4f* S = (v4f*)(slocal + (((size_t)bh * 32 + chunk) * 128 + p) * 64);
    #pragma unroll
    for (int i = 0; i < 16; ++i) S[i] = hs[i];
}

__global__ __launch_bounds__(128) void scan_comb(
    const float* __restrict__ slocal, const float* __restrict__ cdec,
    float* __restrict__ hinit)
{
    int bh = blockIdx.x, p = threadIdx.x;
    v4f hi[16] = {};
    for (int c = 0; c < 32; ++c) {
        size_t off = (((size_t)bh * 32 + c) * 128 + p) * 64;
        v4f* H = (v4f*)(hinit + off);
        const v4f* S = (const v4f*)(slocal + off);
        float cd = cdec[bh * 32 + c];
        #pragma unroll
        for (int i = 0; i < 16; ++i) { H[i] = hi[i]; hi[i] = hi[i] * cd + S[i]; }
    }
}

__global__ __launch_bounds__(128) void scan_p3(
    const float* __restrict__ conv, const float* __restrict__ dtb,
    const float* __restrict__ decb, const float* __restrict__ hinit,
    const float* __restrict__ Dskip, float* __restrict__ ybuf)
{
    int chunk = blockIdx.x, bh = blockIdx.y;
    int b = bh >> 3, h = bh & 7, p = threadIdx.x;
    v4f hs[16];
    const v4f* H = (const v4f*)(hinit + (((size_t)bh * 32 + chunk) * 128 + p) * 64);
    #pragma unroll
    for (int i = 0; i < 16; ++i) hs[i] = H[i];
    const float* cb_ = conv + (size_t)b * 2048 * 1152;
    float Dk = Dskip[h];
    int t0 = chunk * 64;
    for (int t = 0; t < 64; ++t) {
        int tt = t0 + t;
        int ri = (b * 2048 + tt) * 8 + h;
        float dtv = dtb[ri], dec = decb[ri];
        float xv = cb_[(size_t)tt * 1152 + h * 128 + p];
        float c1 = dtv * xv;
        const v4f* Bp = (const v4f*)(cb_ + (size_t)tt * 1152 + 1024);
        const v4f* Cp = (const v4f*)(cb_ + (size_t)tt * 1152 + 1088);
        v4f ya = {0.f, 0.f, 0.f, 0.f};
        #pragma unroll
        for (int i = 0; i < 16; ++i) {
            hs[i] = hs[i] * dec + Bp[i] * c1;
            ya += hs[i] * Cp[i];
        }
        float y = ya[0] + ya[1] + ya[2] + ya[3];
        ybuf[((size_t)(b * 2048 + tt)) * 1024 + h * 128 + p] = y + Dk * xv;
    }
}

// ---------------- gate (y * silu(z)) + RMSNorm -> bf16 ----------------
__global__ __launch_bounds__(256) void gate_rms(
    const float* __restrict__ ybuf, const float* __restrict__ zx,
    const float* __restrict__ rms_w, bf16* __restrict__ out)
{
    int row = blockIdx.x, tid = threadIdx.x;
    float vals[4];
    float ss = 0.f;
    #pragma unroll
    for (int j = 0; j < 4; ++j) {
        int i = tid + j * 256;
        float y = ybuf[(size_t)row * 1024 + i];
        float zv = zx[(size_t)row * 2184 + i];
        float g = y * (zv / (1.f + expf(-zv)));
        vals[j] = g;
        ss += g * g;
    }
    #pragma unroll
    for (int o = 32; o; o >>= 1) ss += __shfl_xor(ss, o);
    __shared__ float l[4];
    if ((tid & 63) == 0) l[tid >> 6] = ss;
    __syncthreads();
    ss = l[0] + l[1] + l[2] + l[3];
    float rs = rsqrtf(ss * (1.f / 1024.f) + 1e-5f);
    #pragma unroll
    for (int j = 0; j < 4; ++j) {
        int i = tid + j * 256;
        out[(size_t)row * 1024 + i] = __float2bfloat16(vals[j] * rs * rms_w[i]);
    }
}

// ---------------- softmax over 1024 bf16 scores (in place), scale 1/8 ----------------
__global__ __launch_bounds__(256) void softmax_bf(bf16* __restrict__ sc) {
    size_t row = blockIdx.x;
    int tid = threadIdx.x;
    bf16* r = sc + row * 1024;
    float v[4];
    #pragma unroll
    for (int j = 0; j < 4; ++j) v[j] = 0.125f * __bfloat162float(r[tid + j * 256]);
    float m = fmaxf(fmaxf(v[0], v[1]), fmaxf(v[2], v[3]));
    #pragma unroll
    for (int o = 32; o; o >>= 1) m = fmaxf(m, __shfl_xor(m, o));
    __shared__ float l[4], l2[4];
    if ((tid & 63) == 0) l[tid >> 6] = m;
    __syncthreads();
    m = fmaxf(fmaxf(l[0], l[1]), fmaxf(l[2], l[3]));
    float s = 0.f;
    #pragma unroll
    for (int j = 0; j < 4; ++j) { v[j] = expf(v[j] - m); s += v[j]; }
    #pragma unroll
    for (int o = 32; o; o >>= 1) s += __shfl_xor(s, o);
    if ((tid & 63) == 0) l2[tid >> 6] = s;
    __syncthreads();
    s = l2[0] + l2[1] + l2[2] + l2[3];
    float inv = 1.f / s;
    #pragma unroll
    for (int j = 0; j < 4; ++j) r[tid + j * 256] = __float2bfloat16(v[j] * inv);
}

// ---------------- V transpose: [b,m,h*64+d] -> [(b*8+h), d, m] ----------------
__global__ void v_transpose(const bf16* __restrict__ v, bf16* __restrict__ vT) {
    int idx = blockIdx.x * 256 + threadIdx.x;  // 2*1024*512
    if (idx >= 2 * 1024 * 512) return;
    int c = idx & 511;
    int m = (idx >> 9) & 1023;
    int b = idx >> 19;
    int h = c >> 6, d = c & 63;
    vT[(((size_t)(b * 8 + h) * 64) + d) * 1024 + m] = v[idx];
}

extern "C" void kernel_launch(void* const* d_in, const int* in_sizes, int n_in,
                              void* d_out, int out_size, void* d_ws, size_t ws_size,
                              hipStream_t stream) {
    (void)in_sizes; (void)n_in; (void)out_size; (void)ws_size;
    const float* x       = (const float*)d_in[0];
    const float* memory  = (const float*)d_in[1];
    const float* mask    = (const float*)d_in[2];
    const float* ln1_g   = (const float*)d_in[3];
    const float* ln1_b   = (const float*)d_in[4];
    const float* ln2_g   = (const float*)d_in[5];
    const float* ln2_b   = (const float*)d_in[6];
    const float* W_in    = (const float*)d_in[7];
    const float* conv_w  = (const float*)d_in[8];
    const float* conv_b  = (const float*)d_in[9];
    const float* dt_bias = (const float*)d_in[10];
    const float* A_log   = (const float*)d_in[11];
    const float* D_skip  = (const float*)d_in[12];
    const float* rms_w   = (const float*)d_in[13];
    const float* W_out   = (const float*)d_in[14];
    const float* Wqkv    = (const float*)d_in[15];
    const float* bqkv    = (const float*)d_in[16];
    const float* Wo      = (const float*)d_in[17];
    const float* bo      = (const float*)d_in[18];
    float* out = (float*)d_out;

    char* w = (char*)d_ws;
    bf16*  xn     = (bf16*)(w + 0);           // 4096x512
    bf16*  Winb   = (bf16*)(w + 4194304);     // 2184x512
    bf16*  Woutb  = (bf16*)(w + 6430720);     // 512x1024
    bf16*  Wqkvb  = (bf16*)(w + 7479296);     // 1536x512
    bf16*  Wob    = (bf16*)(w + 9052160);     // 512x512
    bf16*  memb   = (bf16*)(w + 9576448);     // 2048x512
    float* zx     = (float*)(w + 11673600);   // 4096x2184
    float* conv   = (float*)(w + 47456256);   // 4096x1152
    float* dtb    = (float*)(w + 66330624);   // 4096x8
    float* decb   = (float*)(w + 66461696);   // 4096x8
    float* ybuf   = (float*)(w + 66592768);   // 4096x1024
    bf16*  scores = (bf16*)(w + 11673600);    // overlay regionC: [2,8,2048,1024]
    float* slocal = (float*)(w + 83369984);   // 16x32x128x64
    float* hinit  = (float*)(w + 100147200);  // 16x32x128x64
    bf16*  ybf    = (bf16*)(w + 83369984);    // overlay slocal: 4096x1024
    float* x2     = (float*)(w + 100147200);  // overlay hinit: 4096x512
    bf16*  hb     = (bf16*)(w + 108535808);   // 4096x512
    bf16*  qb     = (bf16*)(w + 112730112);   // 4096x512
    float* cdec   = (float*)(w + 116924416);  // 16x32
    bf16*  kb     = (bf16*)(w + 116928512);   // 2048x512
    bf16*  vb     = (bf16*)(w + 119025664);   // 2048x512
    bf16*  vT     = (bf16*)(w + 121122816);   // 16x64x1024
    bf16*  attn   = (bf16*)(w + 123219968);   // 4096x512
    // total ws usage: 127,414,272 bytes

    // weight / memory casts to bf16
    castf2b<<<4368, 256, 0, stream>>>(W_in, Winb, 2184 * 512);
    castf2b<<<2048, 256, 0, stream>>>(W_out, Woutb, 512 * 1024);
    castf2b<<<3072, 256, 0, stream>>>(Wqkv, Wqkvb, 1536 * 512);
    castf2b<<<1024, 256, 0, stream>>>(Wo, Wob, 512 * 512);
    castf2b<<<4096, 256, 0, stream>>>(memory, memb, 2 * 1024 * 512);

    // LN1 (+mask) -> xn (bf16)
    ln_kernel<<<4096, 256, 0, stream>>>(x, ln1_g, ln1_b, mask, xn);

    // in_proj: zx = xn @ W_in^T   [4096 x 2184]
    gemm_bt<<<dim3(32, 18, 1), 256, 0, stream>>>(
        xn, Winb, nullptr, nullptr, (void*)zx,
        4096, 2184, 512, 512, 512, 2184,
        0, 0, 0, 0, 0, 0, 1, 0);

    // depthwise conv + silu on xBC
    conv_silu<<<18432, 256, 0, stream>>>(zx, conv_w, conv_b, conv);
    // dt softplus + decay
    dt_prep<<<128, 256, 0, stream>>>(zx, dt_bias, A_log, dtb, decb);

    // chunked scan
    scan_p1<<<dim3(32, 16), 128, 0, stream>>>(conv, dtb, decb, A_log, slocal, cdec);
    scan_comb<<<16, 128, 0, stream>>>(slocal, cdec, hinit);
    scan_p3<<<dim3(32, 16), 128, 0, stream>>>(conv, dtb, decb, hinit, D_skip, ybuf);

    // gate + RMS -> ybf (bf16)
    gate_rms<<<4096, 256, 0, stream>>>(ybuf, zx, rms_w, ybf);

    // out_proj + residual(x) -> x2 (fp32)
    gemm_bt<<<dim3(32, 4, 1), 256, 0, stream>>>(
        ybf, Woutb, nullptr, x, (void*)x2,
        4096, 512, 1024, 1024, 1024, 512,
        0, 0, 0, 0, 0, 0, 1, 0);

    // LN2 -> hb (bf16)
    ln_kernel<<<4096, 256, 0, stream>>>(x2, ln2_g, ln2_b, nullptr, hb);

    // q, k, v projections (bf16 out)
    gemm_bt<<<dim3(32, 4, 1), 256, 0, stream>>>(
        hb, Wqkvb, bqkv, nullptr, (void*)qb,
        4096, 512, 512, 512, 512, 512, 0, 0, 0, 0, 0, 0, 1, 1);
    gemm_bt<<<dim3(16, 4, 1), 256, 0, stream>>>(
        memb, Wqkvb + 512 * 512, bqkv + 512, nullptr, (void*)kb,
        2048, 512, 512, 512, 512, 512, 0, 0, 0, 0, 0, 0, 1, 1);
    gemm_bt<<<dim3(16, 4, 1), 256, 0, stream>>>(
        memb, Wqkvb + 1024 * 512, bqkv + 1024, nullptr, (void*)vb,
        2048, 512, 512, 512, 512, 512, 0, 0, 0, 0, 0, 0, 1, 1);

    v_transpose<<<4096, 256, 0, stream>>>(vb, vT);

    // scores = q @ k^T per (b,h)  -> bf16 [2,8,2048,1024]
    gemm_bt<<<dim3(16, 8, 16), 256, 0, stream>>>(
        qb, kb, nullptr, nullptr, (void*)scores,
        2048, 1024, 64, 512, 512, 1024,
        (long)2048 * 512, 64, (long)1024 * 512, 64,
        (long)8 * 2048 * 1024, (long)2048 * 1024, 8, 1);

    softmax_bf<<<32768, 256, 0, stream>>>(scores);

    // attn = P @ V  (via vT), write [b, q, h*64+d]
    gemm_bt<<<dim3(16, 1, 16), 256, 0, stream>>>(
        scores, vT, nullptr, nullptr, (void*)attn,
        2048, 64, 1024, 1024, 1024, 512,
        (long)8 * 2048 * 1024, (long)2048 * 1024,
        (long)8 * 64 * 1024, (long)64 * 1024,
        (long)2048 * 512, 64, 8, 1);

    // final: out = x2 + attn @ Wo^T + bo  (fp32)
    gemm_bt<<<dim3(32, 4, 1), 256, 0, stream>>>(
        attn, Wob, bo, x2, (void*)out,
        4096, 512, 512, 512, 512, 512,
        0, 0, 0, 0, 0, 0, 1, 0);
}

// Round 3
// 447.695 us; speedup vs baseline: 1.2656x; 1.2656x over previous
//
#include <hip/hip_runtime.h>
#include <hip/hip_bf16.h>

typedef __hip_bfloat16 bf16;
typedef short v8s __attribute__((ext_vector_type(8)));
typedef float v4f __attribute__((ext_vector_type(4)));

__device__ __forceinline__ void gll16(const bf16* g, bf16* l) {
    __builtin_amdgcn_global_load_lds(
        (const __attribute__((address_space(1))) unsigned int*)g,
        (__attribute__((address_space(3))) unsigned int*)l, 16, 0, 0);
}

// ---------------- fused f32 -> bf16 casts for all weights ----------------
__global__ __launch_bounds__(256) void cast_all(
    const float* __restrict__ W_in, const float* __restrict__ W_out,
    const float* __restrict__ Wqkv, const float* __restrict__ Wo,
    const float* __restrict__ mem,
    bf16* __restrict__ Winb, bf16* __restrict__ Woutb, bf16* __restrict__ Wqkvb,
    bf16* __restrict__ Wob, bf16* __restrict__ memb)
{
    int i = blockIdx.x * 256 + threadIdx.x;
    const int E0 = 2184 * 512;         // 1,118,208
    const int E1 = E0 + 524288;        // Woutb  512x1024
    const int E2 = E1 + 786432;        // Wqkvb  1536x512
    const int E3 = E2 + 262144;        // Wob    512x512
    const int E4 = E3 + 1048576;       // memb   2048x512 (elements!)
    if (i < E0) {
        Winb[i] = __float2bfloat16(W_in[i]);
    } else if (i < E1) {
        int j = i - E0; Woutb[j] = __float2bfloat16(W_out[j]);
    } else if (i < E2) {
        int j = i - E1; Wqkvb[j] = __float2bfloat16(Wqkv[j]);
    } else if (i < E3) {
        int j = i - E2; Wob[j] = __float2bfloat16(Wo[j]);
    } else if (i < E4) {
        int j = i - E3; memb[j] = __float2bfloat16(mem[j]);
    }
}

// ---------------- layernorm (D=512) -> bf16, optional row mask ----------------
__global__ __launch_bounds__(256) void ln_kernel(
    const float* __restrict__ x, const float* __restrict__ g,
    const float* __restrict__ bt, const float* __restrict__ mask,
    bf16* __restrict__ out)
{
    int row = blockIdx.x, tid = threadIdx.x;
    const float* xr = x + (size_t)row * 512;
    float v0 = xr[tid], v1 = xr[tid + 256];
    float s = v0 + v1, ss = v0 * v0 + v1 * v1;
    #pragma unroll
    for (int o = 32; o; o >>= 1) { s += __shfl_xor(s, o); ss += __shfl_xor(ss, o); }
    __shared__ float l1[4], l2[4];
    if ((tid & 63) == 0) { l1[tid >> 6] = s; l2[tid >> 6] = ss; }
    __syncthreads();
    s = l1[0] + l1[1] + l1[2] + l1[3];
    ss = l2[0] + l2[1] + l2[2] + l2[3];
    float mean = s * (1.f / 512.f);
    float var = ss * (1.f / 512.f) - mean * mean;
    float rs = rsqrtf(var + 1e-5f);
    float mk = mask ? mask[row] : 1.f;
    out[(size_t)row * 512 + tid] =
        __float2bfloat16(((v0 - mean) * rs * g[tid] + bt[tid]) * mk);
    out[(size_t)row * 512 + tid + 256] =
        __float2bfloat16(((v1 - mean) * rs * g[tid + 256] + bt[tid + 256]) * mk);
}

// ---------------- generic bf16 MFMA GEMM: C = A @ W^T (+bias +resid) ----------------
// A: [M x K] row-major bf16 (ldA), W: [N x K] row-major bf16 (ldW).
// W-tile rows beyond N are read (must stay inside d_ws!) but never stored:
// the epilogue guards col < N. C: [M x N] (ldC) fp32 or bf16.
// Batched via blockIdx.z: off = (z/zdiv)*s1 + (z%zdiv)*s2.
__global__ __launch_bounds__(256) void gemm_bt(
    const bf16* __restrict__ Aall, const bf16* __restrict__ Wall,
    const float* __restrict__ bias, const float* __restrict__ resid,
    void* __restrict__ Cout,
    int M, int N, int K, int ldA, int ldW, int ldC,
    long sA1, long sA2, long sW1, long sW2, long sC1, long sC2,
    int zdiv, int outbf16)
{
    __shared__ bf16 lA[128 * 32];
    __shared__ bf16 lB[128 * 32];
    int z = blockIdx.z;
    int zb = z / zdiv, zh = z - zb * zdiv;
    const bf16* A = Aall + zb * sA1 + zh * sA2;
    const bf16* W = Wall + zb * sW1 + zh * sW2;
    long coff = zb * sC1 + zh * sC2;

    int bm = blockIdx.x * 128, bn = blockIdx.y * 128;
    int tid = threadIdx.x, lane = tid & 63, wv = tid >> 6;
    int wr = (wv >> 1) * 64, wc = (wv & 1) * 64;
    int lr15 = lane & 15, lk8 = (lane >> 4) * 8;

    v4f acc[4][4] = {};
    int sr = tid >> 2, sc = (tid & 3) * 8;
    const bf16* Abase = A + (size_t)(bm + sr) * ldA + sc;
    const bf16* Wbase = W + (size_t)(bn + sr) * ldW + sc;
    bf16* dstA = &lA[tid * 8];
    bf16* dstB = &lB[tid * 8];

    for (int k0 = 0; k0 < K; k0 += 32) {
        __syncthreads();
        gll16(Abase + k0, dstA);
        gll16(Abase + (size_t)64 * ldA + k0, dstA + 2048);
        gll16(Wbase + k0, dstB);
        gll16(Wbase + (size_t)64 * ldW + k0, dstB + 2048);
        __syncthreads();
        v8s af[4], bfr[4];
        #pragma unroll
        for (int i = 0; i < 4; ++i)
            af[i] = *(const v8s*)&lA[(wr + i * 16 + lr15) * 32 + lk8];
        #pragma unroll
        for (int i = 0; i < 4; ++i)
            bfr[i] = *(const v8s*)&lB[(wc + i * 16 + lr15) * 32 + lk8];
        #pragma unroll
        for (int mi = 0; mi < 4; ++mi)
            #pragma unroll
            for (int ni = 0; ni < 4; ++ni)
                acc[mi][ni] = __builtin_amdgcn_mfma_f32_16x16x32_bf16(
                    af[mi], bfr[ni], acc[mi][ni], 0, 0, 0);
    }
    // epilogue: C row = bm+wr+mi*16+(lane>>4)*4+r, col = bn+wc+ni*16+(lane&15)
    int r0 = bm + wr + (lane >> 4) * 4;
    int c0 = bn + wc + lr15;
    #pragma unroll
    for (int mi = 0; mi < 4; ++mi) {
        #pragma unroll
        for (int ni = 0; ni < 4; ++ni) {
            int col = c0 + ni * 16;
            if (col < N) {
                float bv = bias ? bias[col] : 0.f;
                #pragma unroll
                for (int r = 0; r < 4; ++r) {
                    int row = r0 + mi * 16 + r;
                    long idx = coff + (long)row * ldC + col;
                    float v = acc[mi][ni][r] + bv;
                    if (resid) v += resid[idx];
                    if (outbf16) ((bf16*)Cout)[idx] = __float2bfloat16(v);
                    else ((float*)Cout)[idx] = v;
                }
            }
        }
    }
}

// ---------------- causal depthwise conv (K=4) + bias + silu ----------------
__global__ __launch_bounds__(256) void conv_silu(
    const float* __restrict__ zx, const float* __restrict__ cw,
    const float* __restrict__ cb, float* __restrict__ out)
{
    int idx = blockIdx.x * 256 + threadIdx.x;  // B*S*1152
    if (idx >= 2 * 2048 * 1152) return;
    int c = idx % 1152;
    int t = (idx / 1152) % 2048;
    int b = idx / (1152 * 2048);
    const float* base = zx + (size_t)b * 2048 * 2184 + 1024 + c;
    float acc = cb[c];
    #pragma unroll
    for (int j = 0; j < 4; ++j) {
        int ts = t - 3 + j;
        if (ts >= 0) acc += cw[c * 4 + j] * base[(size_t)ts * 2184];
    }
    out[idx] = acc / (1.f + expf(-acc));
}

// ---------------- dt softplus + decay precompute ----------------
__global__ void dt_prep(const float* __restrict__ zx, const float* __restrict__ dt_bias,
                        const float* __restrict__ A_log,
                        float* __restrict__ dtb, float* __restrict__ decb)
{
    int i = blockIdx.x * 256 + threadIdx.x;  // 4096*8
    if (i >= 32768) return;
    int h = i & 7, row = i >> 3;
    float d = zx[(size_t)row * 2184 + 2176 + h] + dt_bias[h];
    float sp = d > 20.f ? d : log1pf(expf(d));
    dtb[i] = sp;
    decb[i] = expf(-expf(A_log[h]) * sp);
}

// ---------------- chunked SSM scan ----------------
__global__ __launch_bounds__(128) void scan_p1(
    const float* __restrict__ conv, const float* __restrict__ dtb,
    const float* __restrict__ decb, const float* __restrict__ A_log,
    float* __restrict__ slocal, float* __restrict__ cdec)
{
    int chunk = blockIdx.x, bh = blockIdx.y;
    int b = bh >> 3, h = bh & 7, p = threadIdx.x;
    v4f hs[16] = {};
    const float* cb_ = conv + (size_t)b * 2048 * 1152;
    float sdt = 0.f;
    int t0 = chunk * 64;
    for (int t = 0; t < 64; ++t) {
        int tt = t0 + t;
        int ri = (b * 2048 + tt) * 8 + h;
        float dtv = dtb[ri], dec = decb[ri];
        float xv = cb_[(size_t)tt * 1152 + h * 128 + p];
        float c1 = dtv * xv;
        const v4f* Bp = (const v4f*)(cb_ + (size_t)tt * 1152 + 1024);
        #pragma unroll
        for (int i = 0; i < 16; ++i) hs[i] = hs[i] * dec + Bp[i] * c1;
        sdt += dtv;
    }
    if (p == 0) cdec[bh * 32 + chunk] = expf(-expf(A_log[h]) * sdt);
    v4f* S = (v4f*)(slocal + (((size_t)bh * 32 + chunk) * 128 + p) * 64);
    #pragma unroll
    for (int i = 0; i < 16; ++i) S[i] = hs[i];
}

// parallel chunk-prefix: one thread per state element (bh,p,n)
__global__ __launch_bounds__(256) void scan_comb(
    const float* __restrict__ slocal, const float* __restrict__ cdec,
    float* __restrict__ hinit)
{
    int e = blockIdx.x * 256 + threadIdx.x;  // 16*128*64 = 131072
    int n = e & 63, p = (e >> 6) & 127, bh = e >> 13;
    size_t base = ((size_t)bh * 32 * 128 + p) * 64 + n;
    float hi = 0.f;
    #pragma unroll
    for (int c = 0; c < 32; ++c) {
        size_t idx = base + (size_t)c * 8192;
        hinit[idx] = hi;
        hi = hi * cdec[bh * 32 + c] + slocal[idx];
    }
}

__global__ __launch_bounds__(128) void scan_p3(
    const float* __restrict__ conv, const float* __restrict__ dtb,
    const float* __restrict__ decb, const float* __restrict__ hinit,
    const float* __restrict__ Dskip, float* __restrict__ ybuf)
{
    int chunk = blockIdx.x, bh = blockIdx.y;
    int b = bh >> 3, h = bh & 7, p = threadIdx.x;
    v4f hs[16];
    const v4f* H = (const v4f*)(hinit + (((size_t)bh * 32 + chunk) * 128 + p) * 64);
    #pragma unroll
    for (int i = 0; i < 16; ++i) hs[i] = H[i];
    const float* cb_ = conv + (size_t)b * 2048 * 1152;
    float Dk = Dskip[h];
    int t0 = chunk * 64;
    for (int t = 0; t < 64; ++t) {
        int tt = t0 + t;
        int ri = (b * 2048 + tt) * 8 + h;
        float dtv = dtb[ri], dec = decb[ri];
        float xv = cb_[(size_t)tt * 1152 + h * 128 + p];
        float c1 = dtv * xv;
        const v4f* Bp = (const v4f*)(cb_ + (size_t)tt * 1152 + 1024);
        const v4f* Cp = (const v4f*)(cb_ + (size_t)tt * 1152 + 1088);
        v4f ya = {0.f, 0.f, 0.f, 0.f};
        #pragma unroll
        for (int i = 0; i < 16; ++i) {
            hs[i] = hs[i] * dec + Bp[i] * c1;
            ya += hs[i] * Cp[i];
        }
        float y = ya[0] + ya[1] + ya[2] + ya[3];
        ybuf[((size_t)(b * 2048 + tt)) * 1024 + h * 128 + p] = y + Dk * xv;
    }
}

// ---------------- gate (y * silu(z)) + RMSNorm -> bf16 ----------------
__global__ __launch_bounds__(256) void gate_rms(
    const float* __restrict__ ybuf, const float* __restrict__ zx,
    const float* __restrict__ rms_w, bf16* __restrict__ out)
{
    int row = blockIdx.x, tid = threadIdx.x;
    float vals[4];
    float ss = 0.f;
    #pragma unroll
    for (int j = 0; j < 4; ++j) {
        int i = tid + j * 256;
        float y = ybuf[(size_t)row * 1024 + i];
        float zv = zx[(size_t)row * 2184 + i];
        float g = y * (zv / (1.f + expf(-zv)));
        vals[j] = g;
        ss += g * g;
    }
    #pragma unroll
    for (int o = 32; o; o >>= 1) ss += __shfl_xor(ss, o);
    __shared__ float l[4];
    if ((tid & 63) == 0) l[tid >> 6] = ss;
    __syncthreads();
    ss = l[0] + l[1] + l[2] + l[3];
    float rs = rsqrtf(ss * (1.f / 1024.f) + 1e-5f);
    #pragma unroll
    for (int j = 0; j < 4; ++j) {
        int i = tid + j * 256;
        out[(size_t)row * 1024 + i] = __float2bfloat16(vals[j] * rs * rms_w[i]);
    }
}

// ---------------- softmax over 1024 bf16 scores (in place), scale 1/8 ----------------
__global__ __launch_bounds__(256) void softmax_bf(bf16* __restrict__ sc) {
    size_t row = blockIdx.x;
    int tid = threadIdx.x;
    bf16* r = sc + row * 1024;
    float v[4];
    #pragma unroll
    for (int j = 0; j < 4; ++j) v[j] = 0.125f * __bfloat162float(r[tid + j * 256]);
    float m = fmaxf(fmaxf(v[0], v[1]), fmaxf(v[2], v[3]));
    #pragma unroll
    for (int o = 32; o; o >>= 1) m = fmaxf(m, __shfl_xor(m, o));
    __shared__ float l[4], l2[4];
    if ((tid & 63) == 0) l[tid >> 6] = m;
    __syncthreads();
    m = fmaxf(fmaxf(l[0], l[1]), fmaxf(l[2], l[3]));
    float s = 0.f;
    #pragma unroll
    for (int j = 0; j < 4; ++j) { v[j] = expf(v[j] - m); s += v[j]; }
    #pragma unroll
    for (int o = 32; o; o >>= 1) s += __shfl_xor(s, o);
    if ((tid & 63) == 0) l2[tid >> 6] = s;
    __syncthreads();
    s = l2[0] + l2[1] + l2[2] + l2[3];
    float inv = 1.f / s;
    #pragma unroll
    for (int j = 0; j < 4; ++j) r[tid + j * 256] = __float2bfloat16(v[j] * inv);
}

// ---------------- V transpose: [b,m,h*64+d] -> [(b*8+h), d, m] ----------------
__global__ void v_transpose(const bf16* __restrict__ v, bf16* __restrict__ vT) {
    int idx = blockIdx.x * 256 + threadIdx.x;  // 2*1024*512
    if (idx >= 2 * 1024 * 512) return;
    int c = idx & 511;
    int m = (idx >> 9) & 1023;
    int b = idx >> 19;
    int h = c >> 6, d = c & 63;
    vT[(((size_t)(b * 8 + h) * 64) + d) * 1024 + m] = v[idx];
}

extern "C" void kernel_launch(void* const* d_in, const int* in_sizes, int n_in,
                              void* d_out, int out_size, void* d_ws, size_t ws_size,
                              hipStream_t stream) {
    (void)in_sizes; (void)n_in; (void)out_size; (void)ws_size;
    const float* x       = (const float*)d_in[0];
    const float* memory  = (const float*)d_in[1];
    const float* mask    = (const float*)d_in[2];
    const float* ln1_g   = (const float*)d_in[3];
    const float* ln1_b   = (const float*)d_in[4];
    const float* ln2_g   = (const float*)d_in[5];
    const float* ln2_b   = (const float*)d_in[6];
    const float* W_in    = (const float*)d_in[7];
    const float* conv_w  = (const float*)d_in[8];
    const float* conv_b  = (const float*)d_in[9];
    const float* dt_bias = (const float*)d_in[10];
    const float* A_log   = (const float*)d_in[11];
    const float* D_skip  = (const float*)d_in[12];
    const float* rms_w   = (const float*)d_in[13];
    const float* W_out   = (const float*)d_in[14];
    const float* Wqkv    = (const float*)d_in[15];
    const float* bqkv    = (const float*)d_in[16];
    const float* Wo      = (const float*)d_in[17];
    const float* bo      = (const float*)d_in[18];
    float* out = (float*)d_out;

    char* w = (char*)d_ws;
    bf16*  xn     = (bf16*)(w + 0);           // 4096x512
    bf16*  Winb   = (bf16*)(w + 4194304);     // 2184x512
    bf16*  Woutb  = (bf16*)(w + 6430720);     // 512x1024
    bf16*  Wqkvb  = (bf16*)(w + 7479296);     // 1536x512
    bf16*  Wob    = (bf16*)(w + 9052160);     // 512x512
    bf16*  memb   = (bf16*)(w + 9576448);     // 2048x512
    float* zx     = (float*)(w + 11673600);   // 4096x2184
    float* conv   = (float*)(w + 47456256);   // 4096x1152
    float* dtb    = (float*)(w + 66330624);   // 4096x8
    float* decb   = (float*)(w + 66461696);   // 4096x8
    float* ybuf   = (float*)(w + 66592768);   // 4096x1024
    bf16*  scores = (bf16*)(w + 11673600);    // overlay zx..ybuf (dead by then)
    float* slocal = (float*)(w + 83369984);   // 16x32x128x64
    float* hinit  = (float*)(w + 100147200);  // 16x32x128x64
    bf16*  ybf    = (bf16*)(w + 83369984);    // overlay slocal
    float* x2     = (float*)(w + 100147200);  // overlay hinit (first 8MB)
    bf16*  hb     = (bf16*)(w + 108535808);   // 4096x512 (overlay hinit tail)
    bf16*  qb     = (bf16*)(w + 112730112);   // 4096x512 (overlay hinit tail)
    float* cdec   = (float*)(w + 116924416);  // 16x32
    bf16*  kb     = (bf16*)(w + 116928512);   // 2048x512
    bf16*  vb     = (bf16*)(w + 119025664);   // 2048x512
    bf16*  vT     = (bf16*)(w + 121122816);   // 16x64x1024
    bf16*  attn   = (bf16*)(w + 123219968);   // 4096x512
    // total ws usage: 127,414,272 bytes (same as round-1 proven layout)

    cast_all<<<14608, 256, 0, stream>>>(W_in, W_out, Wqkv, Wo, memory,
                                        Winb, Woutb, Wqkvb, Wob, memb);

    ln_kernel<<<4096, 256, 0, stream>>>(x, ln1_g, ln1_b, mask, xn);

    // in_proj: zx = xn @ W_in^T   [4096 x 2184]
    gemm_bt<<<dim3(32, 18, 1), 256, 0, stream>>>(
        xn, Winb, nullptr, nullptr, (void*)zx,
        4096, 2184, 512, 512, 512, 2184,
        0, 0, 0, 0, 0, 0, 1, 0);

    conv_silu<<<18432, 256, 0, stream>>>(zx, conv_w, conv_b, conv);
    dt_prep<<<128, 256, 0, stream>>>(zx, dt_bias, A_log, dtb, decb);

    scan_p1<<<dim3(32, 16), 128, 0, stream>>>(conv, dtb, decb, A_log, slocal, cdec);
    scan_comb<<<512, 256, 0, stream>>>(slocal, cdec, hinit);
    scan_p3<<<dim3(32, 16), 128, 0, stream>>>(conv, dtb, decb, hinit, D_skip, ybuf);

    gate_rms<<<4096, 256, 0, stream>>>(ybuf, zx, rms_w, ybf);

    // out_proj + residual(x) -> x2 (fp32)
    gemm_bt<<<dim3(32, 4, 1), 256, 0, stream>>>(
        ybf, Woutb, nullptr, x, (void*)x2,
        4096, 512, 1024, 1024, 1024, 512,
        0, 0, 0, 0, 0, 0, 1, 0);

    ln_kernel<<<4096, 256, 0, stream>>>(x2, ln2_g, ln2_b, nullptr, hb);

    gemm_bt<<<dim3(32, 4, 1), 256, 0, stream>>>(
        hb, Wqkvb, bqkv, nullptr, (void*)qb,
        4096, 512, 512, 512, 512, 512, 0, 0, 0, 0, 0, 0, 1, 1);
    gemm_bt<<<dim3(16, 4, 1), 256, 0, stream>>>(
        memb, Wqkvb + 512 * 512, bqkv + 512, nullptr, (void*)kb,
        2048, 512, 512, 512, 512, 512, 0, 0, 0, 0, 0, 0, 1, 1);
    gemm_bt<<<dim3(16, 4, 1), 256, 0, stream>>>(
        memb, Wqkvb + 1024 * 512, bqkv + 1024, nullptr, (void*)vb,
        2048, 512, 512, 512, 512, 512, 0, 0, 0, 0, 0, 0, 1, 1);

    v_transpose<<<4096, 256, 0, stream>>>(vb, vT);

    // scores = q @ k^T per (b,h)  -> bf16 [2,8,2048,1024]
    gemm_bt<<<dim3(16, 8, 16), 256, 0, stream>>>(
        qb, kb, nullptr, nullptr, (void*)scores,
        2048, 1024, 64, 512, 512, 1024,
        (long)2048 * 512, 64, (long)1024 * 512, 64,
        (long)8 * 2048 * 1024, (long)2048 * 1024, 8, 1);

    softmax_bf<<<32768, 256, 0, stream>>>(scores);

    // attn = P @ V  (via vT), write [b, q, h*64+d]
    gemm_bt<<<dim3(16, 1, 16), 256, 0, stream>>>(
        scores, vT, nullptr, nullptr, (void*)attn,
        2048, 64, 1024, 1024, 1024, 512,
        (long)8 * 2048 * 1024, (long)2048 * 1024,
        (long)8 * 64 * 1024, (long)64 * 1024,
        (long)2048 * 512, 64, 8, 1);

    // final: out = x2 + attn @ Wo^T + bo  (fp32)
    gemm_bt<<<dim3(32, 4, 1), 256, 0, stream>>>(
        attn, Wob, bo, x2, (void*)out,
        4096, 512, 512, 512, 512, 512,
        0, 0, 0, 0, 0, 0, 1, 0);
}